// Round 3
// baseline (149.317 us; speedup 1.0000x reference)
//
#include <hip/hip_runtime.h>

// MpMaxPoolingMatch: out[b,t,m] = tanh( max_s sum_d lt[b,t,d]*km[m,d]*rt[b,s,d] )
// B=32, T=256, D=512, MP=20.
// R3: phase-1 = trivial coalesced fp32->bf16 cast (row-major, no transpose).
// Main: B staged to LDS via global_load_lds into row-major k-slabs ([row][32] bf16,
// 64B rows — DMA-compatible AND conflict-free b128 frag reads); A-frags loaded
// directly from L2 (global dwordx4, 1-step prefetch) and km-scaled in-register;
// XCD swizzle keeps each b's tiles L2-resident. One barrier per K-step.

constexpr int TT = 256;   // T
constexpr int DD = 512;   // D
constexpr int NM = 20;    // MP
constexpr int NB = 32;    // B
constexpr int BM = 128;
constexpr int BN = 256;
constexpr int BK = 32;
constexpr int NK = DD / BK;   // 16

typedef short bf16x8 __attribute__((ext_vector_type(8)));
typedef float f32x4  __attribute__((ext_vector_type(4)));

__device__ __forceinline__ void async_ld16(const void* g, void* l) {
    __builtin_amdgcn_global_load_lds(
        (const __attribute__((address_space(1))) void*)g,
        (__attribute__((address_space(3))) void*)l, 16, 0, 0);
}

__device__ __forceinline__ unsigned pack_bf16(float lo, float hi) {
    unsigned ulo = __builtin_bit_cast(unsigned, lo);
    unsigned uhi = __builtin_bit_cast(unsigned, hi);
    return (ulo >> 16) | (uhi & 0xFFFF0000u);
}

// scale packed bf16 pair (lo=elem k, hi=elem k+1) by f32 k0,k1; repack (truncate)
__device__ __forceinline__ unsigned mulpack(unsigned a2, float k0, float k1) {
    float f0 = __builtin_bit_cast(float, a2 << 16) * k0;
    float f1 = __builtin_bit_cast(float, a2 & 0xFFFF0000u) * k1;
    return __builtin_amdgcn_perm(__builtin_bit_cast(unsigned, f1),
                                 __builtin_bit_cast(unsigned, f0), 0x07060302u);
}

// ---------------- Phase 1: coalesced fp32 -> bf16 cast, row-major ----------------
// 2048 blocks per tensor, 8 elems/thread. No LDS, no transpose.
__global__ __launch_bounds__(256)
void cast_bf16(const float* __restrict__ lt, const float* __restrict__ rt,
               unsigned short* __restrict__ ltb, unsigned short* __restrict__ rtb)
{
    const int half = (int)gridDim.x >> 1;
    int bid = blockIdx.x;
    const float* src;
    unsigned short* dst;
    if (bid < half) { src = lt; dst = ltb; }
    else            { src = rt; dst = rtb; bid -= half; }
    size_t base = ((size_t)bid * 256 + threadIdx.x) * 8;
    float4 a = *(const float4*)(src + base);
    float4 b = *(const float4*)(src + base + 4);
    uint4 w;
    w.x = pack_bf16(a.x, a.y);
    w.y = pack_bf16(a.z, a.w);
    w.z = pack_bf16(b.x, b.y);
    w.w = pack_bf16(b.z, b.w);
    *(uint4*)(dst + base) = w;
}

// ---------------- Main kernel ----------------
__global__ __launch_bounds__(256, 2)
void mp_match_main(const unsigned short* __restrict__ ltb, const unsigned short* __restrict__ rtb,
                   const float* __restrict__ km, float* __restrict__ out)
{
    __shared__ __attribute__((aligned(16))) unsigned short Bsh[2][BN][BK]; // 32 KB
    __shared__ __attribute__((aligned(16))) float kmf[DD];                 // 2 KB
    __shared__ __attribute__((aligned(16))) float maxbuf[2][BM];           // 1 KB

    // XCD swizzle: blocks with flat%8==c land on XCD c; give XCD c the b's with b%8==c.
    const int f = blockIdx.x;            // 0..1279
    const int c = f & 7;
    const int i = f >> 3;                // 0..159
    const int b = c + 8 * (i / 40);      // 0..31
    const int j = i % 40;
    const int m = j >> 1;                // 0..19
    const int ttile = j & 1;             // 0..1
    const int t0 = ttile * BM;

    const int tid  = threadIdx.x;
    const int w    = tid >> 6;
    const int lane = tid & 63;
    const int l15  = lane & 15;
    const int l4   = lane >> 4;
    const int wt   = (w & 1) * 64;   // wave's t offset within tile
    const int wsi  = w >> 1;         // wave's s-half

    kmf[tid]       = km[(size_t)m * DD + tid];
    kmf[tid + 256] = km[(size_t)m * DD + tid + 256];

    const unsigned short* ltB = ltb + ((size_t)b * TT + t0) * DD;
    const unsigned short* rtB = rtb + (size_t)b * TT * DD;
    // A-frag base for this lane: row = wt + l15 (+16 per frag i), k = l4*8 (+kb)
    const unsigned short* aRow = ltB + (size_t)(wt + l15) * DD + l4 * 8;

    auto issueB = [&](int kk, int buf) {
        const int kb = kk * BK;
#pragma unroll
        for (int q = 0; q < 4; ++q) {
            int slot = q * 256 + tid;                       // = wave-uniform + lane
            const unsigned short* src = rtB + (size_t)(slot >> 2) * DD + kb + (slot & 3) * 8;
            async_ld16(src, (char*)&Bsh[buf][0][0] + (size_t)slot * 16);
        }
    };
    auto loadA = [&](int kk, uint4* ar) {
        const int kb = kk * BK;
#pragma unroll
        for (int ii = 0; ii < 4; ++ii)
            ar[ii] = *(const uint4*)(aRow + (size_t)ii * 16 * DD + kb);
    };

    f32x4 acc[4][8] = {};
    uint4 arC[4], arN[4];

    issueB(0, 0);
    loadA(0, arC);
    __syncthreads();   // kmf written; DMA(0) + arC drained by compiler waitcnt at barrier

    for (int kk = 0; kk < NK; ++kk) {
        const int buf = kk & 1;
        if (kk + 1 < NK) {
            issueB(kk + 1, buf ^ 1);   // in flight through this step's compute
            loadA(kk + 1, arN);
        }
        float4 k0 = *(const float4*)&kmf[kk * BK + l4 * 8];
        float4 k1 = *(const float4*)&kmf[kk * BK + l4 * 8 + 4];
        bf16x8 bv[8];
#pragma unroll
        for (int jj = 0; jj < 8; ++jj)
            bv[jj] = *(const bf16x8*)&Bsh[buf][wsi * 128 + jj * 16 + l15][l4 * 8];
        bf16x8 af[4];
#pragma unroll
        for (int ii = 0; ii < 4; ++ii) {
            uint4 a = arC[ii];
            uint4 o;
            o.x = mulpack(a.x, k0.x, k0.y);
            o.y = mulpack(a.y, k0.z, k0.w);
            o.z = mulpack(a.z, k1.x, k1.y);
            o.w = mulpack(a.w, k1.z, k1.w);
            af[ii] = __builtin_bit_cast(bf16x8, o);
        }
#pragma unroll
        for (int ii = 0; ii < 4; ++ii)
#pragma unroll
            for (int jj = 0; jj < 8; ++jj)
                acc[ii][jj] = __builtin_amdgcn_mfma_f32_16x16x32_bf16(af[ii], bv[jj], acc[ii][jj], 0, 0, 0);
#pragma unroll
        for (int ii = 0; ii < 4; ++ii) arC[ii] = arN[ii];
        if (kk + 1 < NK) __syncthreads();   // DMA(kk+1)+arN landed; buf reads drained
    }

    // ---- Epilogue: max over s, then tanh. C layout: col(s)=lane&15, row(t)=(lane>>4)*4+reg.
#pragma unroll
    for (int ii = 0; ii < 4; ++ii) {
        f32x4 v = acc[ii][0];
#pragma unroll
        for (int jj = 1; jj < 8; ++jj) {
            v.x = fmaxf(v.x, acc[ii][jj].x);
            v.y = fmaxf(v.y, acc[ii][jj].y);
            v.z = fmaxf(v.z, acc[ii][jj].z);
            v.w = fmaxf(v.w, acc[ii][jj].w);
        }
#pragma unroll
        for (int off = 1; off < 16; off <<= 1) {
            v.x = fmaxf(v.x, __shfl_xor(v.x, off, 64));
            v.y = fmaxf(v.y, __shfl_xor(v.y, off, 64));
            v.z = fmaxf(v.z, __shfl_xor(v.z, off, 64));
            v.w = fmaxf(v.w, __shfl_xor(v.w, off, 64));
        }
        if (l15 == 0)
            *(f32x4*)&maxbuf[wsi][wt + ii * 16 + l4 * 4] = v;
    }
    __syncthreads();
    if (tid < BM) {
        float v = fmaxf(maxbuf[0][tid], maxbuf[1][tid]);
        out[((size_t)b * TT + t0 + tid) * NM + m] = tanhf(v);
    }
}

// ---------------- Fallback (R1 known-good, fp32 register staging) ----------------
__global__ __launch_bounds__(256, 2)
void mp_match_kernel(const float* __restrict__ lt, const float* __restrict__ rt,
                     const float* __restrict__ km, float* __restrict__ out)
{
    __shared__ __attribute__((aligned(16))) unsigned short Ash[2][4][BM][8];
    __shared__ __attribute__((aligned(16))) unsigned short Bsh2[2][4][BN][8];
    __shared__ __attribute__((aligned(16))) float maxbuf[2][BM];

    const int ttile = blockIdx.x, m = blockIdx.y, b = blockIdx.z;
    const int t0 = ttile * BM;
    const int tid = threadIdx.x, wave = tid >> 6, lane = tid & 63;
    const int l15 = lane & 15, l4 = lane >> 4;
    const int wt = (wave & 1) * 64, wsi = wave >> 1;

    const float* ltp = lt + ((size_t)b * TT + t0) * DD;
    const float* rtp = rt + (size_t)b * TT * DD;
    const float* kmp = km + (size_t)m * DD;
    const int a_t = tid >> 1, a_h = tid & 1;

    f32x4 acc[4][8] = {};

    auto stage = [&](int kk, int buf) {
        const int d0 = kk * BK;
        const float* ap = ltp + (size_t)a_t * DD + d0 + a_h * 16;
        const float* kp = kmp + d0 + a_h * 16;
#pragma unroll
        for (int q = 0; q < 2; ++q) {
            float4 x0 = *(const float4*)(ap + q * 8);
            float4 x1 = *(const float4*)(ap + q * 8 + 4);
            float4 k0 = *(const float4*)(kp + q * 8);
            float4 k1 = *(const float4*)(kp + q * 8 + 4);
            uint4 wv;
            wv.x = pack_bf16(x0.x * k0.x, x0.y * k0.y);
            wv.y = pack_bf16(x0.z * k0.z, x0.w * k0.w);
            wv.z = pack_bf16(x1.x * k1.x, x1.y * k1.y);
            wv.w = pack_bf16(x1.z * k1.z, x1.w * k1.w);
            *(uint4*)&Ash[buf][a_h * 2 + q][a_t][0] = wv;
        }
        const float* bp = rtp + (size_t)tid * DD + d0;
#pragma unroll
        for (int p = 0; p < 4; ++p) {
            float4 y0 = *(const float4*)(bp + p * 8);
            float4 y1 = *(const float4*)(bp + p * 8 + 4);
            uint4 wv;
            wv.x = pack_bf16(y0.x, y0.y);
            wv.y = pack_bf16(y0.z, y0.w);
            wv.z = pack_bf16(y1.x, y1.y);
            wv.w = pack_bf16(y1.z, y1.w);
            *(uint4*)&Bsh2[buf][p][tid][0] = wv;
        }
    };

    stage(0, 0);
    for (int kk = 0; kk < NK; ++kk) {
        const int buf = kk & 1;
        __syncthreads();
        bf16x8 af[4], bfv[8];
#pragma unroll
        for (int i = 0; i < 4; ++i)
            af[i] = *(const bf16x8*)&Ash[buf][l4][wt + i * 16 + l15][0];
#pragma unroll
        for (int j = 0; j < 8; ++j)
            bfv[j] = *(const bf16x8*)&Bsh2[buf][l4][wsi * 128 + j * 16 + l15][0];
        if (kk + 1 < NK) stage(kk + 1, buf ^ 1);
#pragma unroll
        for (int i = 0; i < 4; ++i)
#pragma unroll
            for (int j = 0; j < 8; ++j)
                acc[i][j] = __builtin_amdgcn_mfma_f32_16x16x32_bf16(af[i], bfv[j], acc[i][j], 0, 0, 0);
    }
#pragma unroll
    for (int i = 0; i < 4; ++i) {
        f32x4 v = acc[i][0];
#pragma unroll
        for (int j = 1; j < 8; ++j) {
            v.x = fmaxf(v.x, acc[i][j].x); v.y = fmaxf(v.y, acc[i][j].y);
            v.z = fmaxf(v.z, acc[i][j].z); v.w = fmaxf(v.w, acc[i][j].w);
        }
#pragma unroll
        for (int off = 1; off < 16; off <<= 1) {
            v.x = fmaxf(v.x, __shfl_xor(v.x, off, 64));
            v.y = fmaxf(v.y, __shfl_xor(v.y, off, 64));
            v.z = fmaxf(v.z, __shfl_xor(v.z, off, 64));
            v.w = fmaxf(v.w, __shfl_xor(v.w, off, 64));
        }
        if (l15 == 0) *(f32x4*)&maxbuf[wsi][wt + i * 16 + l4 * 4] = v;
    }
    __syncthreads();
    if (tid < BM) {
        float v = fmaxf(maxbuf[0][tid], maxbuf[1][tid]);
        out[((size_t)b * TT + t0 + tid) * NM + m] = tanhf(v);
    }
}

extern "C" void kernel_launch(void* const* d_in, const int* in_sizes, int n_in,
                              void* d_out, int out_size, void* d_ws, size_t ws_size,
                              hipStream_t stream) {
    const float* lt  = (const float*)d_in[0];   // (32,256,512) fp32
    const float* rt  = (const float*)d_in[1];   // (32,256,512) fp32
    const float* km  = (const float*)d_in[2];   // (20,512) fp32
    float*       out = (float*)d_out;           // (32,256,20) fp32

    const size_t elems = (size_t)NB * TT * DD;                  // 4,194,304 per tensor
    const size_t need  = 2 * elems * sizeof(unsigned short);    // 16 MB

    if (ws_size >= need) {
        unsigned short* ltb = (unsigned short*)d_ws;
        unsigned short* rtb = ltb + elems;
        const int cast_blocks_per_tensor = (int)(elems / (8 * 256));  // 2048
        cast_bf16<<<cast_blocks_per_tensor * 2, 256, 0, stream>>>(lt, rt, ltb, rtb);
        mp_match_main<<<dim3(1280), 256, 0, stream>>>(ltb, rtb, km, out);
    } else {
        mp_match_kernel<<<dim3(TT / BM, NM, NB), 256, 0, stream>>>(lt, rt, km, out);
    }
}

// Round 5
// 133.559 us; speedup vs baseline: 1.1180x; 1.1180x over previous
//
#include <hip/hip_runtime.h>

// MpMaxPoolingMatch: out[b,t,m] = tanh( max_s sum_d lt[b,t,d]*km[m,d]*rt[b,s,d] )
// B=32, T=256, D=512, MP=20.
// R4 (resubmit; R4 bench was GPUAcquisitionTimeout — never ran):
// phase-1 coalesced fp32->bf16 cast. Main kernel: both A and B staged to LDS
// in row-major 64B-row slabs with chunk-pos XOR swizzle (pos = c ^ ((row>>1)&3))
// -> conflict-free b128 frag reads (2-way max, free) AND global_load_lds-compatible.
// B via DMA (lane picks the global chunk for its fixed LDS slot); A loaded to regs,
// km-scaled (8 mulpacks/thread/step, after MFMA issue), ds_written. XCD swizzle
// keeps each b's bf16 tiles L2-resident. One barrier per K-step.

constexpr int TT = 256;   // T
constexpr int DD = 512;   // D
constexpr int NM = 20;    // MP
constexpr int NB = 32;    // B
constexpr int BM = 128;
constexpr int BN = 256;
constexpr int BK = 32;
constexpr int NK = DD / BK;   // 16

typedef short bf16x8 __attribute__((ext_vector_type(8)));
typedef float f32x4  __attribute__((ext_vector_type(4)));

__device__ __forceinline__ void async_ld16(const void* g, void* l) {
    __builtin_amdgcn_global_load_lds(
        (const __attribute__((address_space(1))) void*)g,
        (__attribute__((address_space(3))) void*)l, 16, 0, 0);
}

__device__ __forceinline__ unsigned pack_bf16(float lo, float hi) {
    unsigned ulo = __builtin_bit_cast(unsigned, lo);
    unsigned uhi = __builtin_bit_cast(unsigned, hi);
    return (ulo >> 16) | (uhi & 0xFFFF0000u);
}

// scale packed bf16 pair (lo=elem k, hi=elem k+1) by f32 k0,k1; repack (truncate)
__device__ __forceinline__ unsigned mulpack(unsigned a2, float k0, float k1) {
    float f0 = __builtin_bit_cast(float, a2 << 16) * k0;
    float f1 = __builtin_bit_cast(float, a2 & 0xFFFF0000u) * k1;
    return __builtin_amdgcn_perm(__builtin_bit_cast(unsigned, f1),
                                 __builtin_bit_cast(unsigned, f0), 0x07060302u);
}

// ---------------- Phase 1: coalesced fp32 -> bf16 cast, row-major ----------------
__global__ __launch_bounds__(256)
void cast_bf16(const float* __restrict__ lt, const float* __restrict__ rt,
               unsigned short* __restrict__ ltb, unsigned short* __restrict__ rtb)
{
    const int half = (int)gridDim.x >> 1;
    int bid = blockIdx.x;
    const float* src;
    unsigned short* dst;
    if (bid < half) { src = lt; dst = ltb; }
    else            { src = rt; dst = rtb; bid -= half; }
    size_t base = ((size_t)bid * 256 + threadIdx.x) * 8;
    float4 a = *(const float4*)(src + base);
    float4 b = *(const float4*)(src + base + 4);
    uint4 w;
    w.x = pack_bf16(a.x, a.y);
    w.y = pack_bf16(a.z, a.w);
    w.z = pack_bf16(b.x, b.y);
    w.w = pack_bf16(b.z, b.w);
    *(uint4*)(dst + base) = w;
}

// ---------------- Main kernel ----------------
__global__ __launch_bounds__(256, 2)
void mp_match_main(const unsigned short* __restrict__ ltb, const unsigned short* __restrict__ rtb,
                   const float* __restrict__ km, float* __restrict__ out)
{
    // chunk-indexed slabs: chunk = row*4 + pos, pos = c ^ ((row>>1)&3), 16B per chunk
    __shared__ __attribute__((aligned(16))) unsigned short Bsh[2][BN * 4 * 8]; // 32 KB
    __shared__ __attribute__((aligned(16))) unsigned short Ash[2][BM * 4 * 8]; // 16 KB
    __shared__ __attribute__((aligned(16))) float kmf[DD];                     // 2 KB
    __shared__ __attribute__((aligned(16))) float maxbuf[2][BM];               // 1 KB

    // XCD swizzle: flat%8 == XCD; give XCD c the b's with b%8==c.
    const int f = blockIdx.x;            // 0..1279
    const int c8 = f & 7;
    const int i = f >> 3;                // 0..159
    const int b = c8 + 8 * (i / 40);     // 0..31
    const int j = i % 40;
    const int m = j >> 1;                // 0..19
    const int t0 = (j & 1) * BM;

    const int tid  = threadIdx.x;
    const int w    = tid >> 6;
    const int lane = tid & 63;
    const int l15  = lane & 15;
    const int l4   = lane >> 4;
    const int wt   = (w & 1) * 64;   // wave's t offset within tile
    const int wsi  = w >> 1;         // wave's s-half

    kmf[tid]       = km[(size_t)m * DD + tid];
    kmf[tid + 256] = km[(size_t)m * DD + tid + 256];

    const unsigned short* ltB = ltb + ((size_t)b * TT + t0) * DD;
    const unsigned short* rtB = rtb + (size_t)b * TT * DD;

    // A staging: thread handles global chunks (row=slot>>2, c=slot&3) for slot=tid, tid+256.
    const int ar0 = tid >> 2,        ac = tid & 3;           // (tid+256)&3 == tid&3
    const int ar1 = (tid + 256) >> 2;
    const int ap0 = ac ^ ((ar0 >> 1) & 3);
    const int ap1 = ac ^ ((ar1 >> 1) & 3);
    const unsigned short* aSrc0 = ltB + (size_t)ar0 * DD + ac * 8;
    const unsigned short* aSrc1 = ltB + (size_t)ar1 * DD + ac * 8;

    auto issueB = [&](int kk, int buf) {
        const int kb = kk * BK;
#pragma unroll
        for (int q = 0; q < 4; ++q) {
            int slot = q * 256 + tid;
            int row = slot >> 2;
            int c = (slot & 3) ^ ((slot >> 3) & 3);          // (row>>1)&3 == (slot>>3)&3
            async_ld16(rtB + (size_t)row * DD + kb + c * 8,
                       (char*)&Bsh[buf][0] + (size_t)slot * 16);
        }
    };
    auto aload = [&](int kk, uint4* ar) {
        ar[0] = *(const uint4*)(aSrc0 + kk * BK);
        ar[1] = *(const uint4*)(aSrc1 + kk * BK);
    };
    auto scaleWrite = [&](int kk, int buf, const uint4* ar) {
        float4 k0 = *(const float4*)&kmf[kk * BK + ac * 8];
        float4 k1 = *(const float4*)&kmf[kk * BK + ac * 8 + 4];
        uint4 o;
        o.x = mulpack(ar[0].x, k0.x, k0.y);
        o.y = mulpack(ar[0].y, k0.z, k0.w);
        o.z = mulpack(ar[0].z, k1.x, k1.y);
        o.w = mulpack(ar[0].w, k1.z, k1.w);
        *(uint4*)&Ash[buf][(size_t)(ar0 * 4 + ap0) * 8] = o;
        o.x = mulpack(ar[1].x, k0.x, k0.y);
        o.y = mulpack(ar[1].y, k0.z, k0.w);
        o.z = mulpack(ar[1].z, k1.x, k1.y);
        o.w = mulpack(ar[1].w, k1.z, k1.w);
        *(uint4*)&Ash[buf][(size_t)(ar1 * 4 + ap1) * 8] = o;
    };

    f32x4 acc[4][8] = {};
    uint4 ar[2];

    aload(0, ar);          // vmcnt ops 1-2 (oldest)
    issueB(0, 0);          // vmcnt ops 3-6
    __syncthreads();       // kmf visible; drains prologue loads+DMA
    scaleWrite(0, 0, ar);

    const int fpos = l4 ^ ((l15 >> 1) & 3);   // swizzled chunk pos for frag reads

    for (int kk = 0; kk < NK; ++kk) {
        const int buf = kk & 1;
        __syncthreads();   // Ash/Bsh[buf] writes visible; prior reads of buf^1 drained
        if (kk + 1 < NK) {
            aload(kk + 1, ar);          // issued BEFORE DMA -> waitable at vmcnt(4)
            issueB(kk + 1, buf ^ 1);    // stays in flight through this step's MFMA
        }
        bf16x8 af[4], bv[8];
#pragma unroll
        for (int ii = 0; ii < 4; ++ii)
            af[ii] = *(const bf16x8*)&Ash[buf][(size_t)((wt + ii * 16 + l15) * 4 + fpos) * 8];
#pragma unroll
        for (int jj = 0; jj < 8; ++jj)
            bv[jj] = *(const bf16x8*)&Bsh[buf][(size_t)((wsi * 128 + jj * 16 + l15) * 4 + fpos) * 8];
#pragma unroll
        for (int ii = 0; ii < 4; ++ii)
#pragma unroll
            for (int jj = 0; jj < 8; ++jj)
                acc[ii][jj] = __builtin_amdgcn_mfma_f32_16x16x32_bf16(af[ii], bv[jj], acc[ii][jj], 0, 0, 0);
        if (kk + 1 < NK)
            scaleWrite(kk + 1, buf ^ 1, ar);   // overlaps MFMA execution; done by next barrier
    }

    // ---- Epilogue: max over s, then tanh. C layout: col(s)=lane&15, row(t)=(lane>>4)*4+reg.
#pragma unroll
    for (int ii = 0; ii < 4; ++ii) {
        f32x4 v = acc[ii][0];
#pragma unroll
        for (int jj = 1; jj < 8; ++jj) {
            v.x = fmaxf(v.x, acc[ii][jj].x);
            v.y = fmaxf(v.y, acc[ii][jj].y);
            v.z = fmaxf(v.z, acc[ii][jj].z);
            v.w = fmaxf(v.w, acc[ii][jj].w);
        }
#pragma unroll
        for (int off = 1; off < 16; off <<= 1) {
            v.x = fmaxf(v.x, __shfl_xor(v.x, off, 64));
            v.y = fmaxf(v.y, __shfl_xor(v.y, off, 64));
            v.z = fmaxf(v.z, __shfl_xor(v.z, off, 64));
            v.w = fmaxf(v.w, __shfl_xor(v.w, off, 64));
        }
        if (l15 == 0)
            *(f32x4*)&maxbuf[wsi][wt + ii * 16 + l4 * 4] = v;
    }
    __syncthreads();
    if (tid < BM) {
        float v = fmaxf(maxbuf[0][tid], maxbuf[1][tid]);
        out[((size_t)b * TT + t0 + tid) * NM + m] = tanhf(v);
    }
}

// ---------------- Fallback (R1 known-good, fp32 register staging) ----------------
__global__ __launch_bounds__(256, 2)
void mp_match_kernel(const float* __restrict__ lt, const float* __restrict__ rt,
                     const float* __restrict__ km, float* __restrict__ out)
{
    __shared__ __attribute__((aligned(16))) unsigned short Ash[2][4][BM][8];
    __shared__ __attribute__((aligned(16))) unsigned short Bsh2[2][4][BN][8];
    __shared__ __attribute__((aligned(16))) float maxbuf[2][BM];

    const int ttile = blockIdx.x, m = blockIdx.y, b = blockIdx.z;
    const int t0 = ttile * BM;
    const int tid = threadIdx.x, wave = tid >> 6, lane = tid & 63;
    const int l15 = lane & 15, l4 = lane >> 4;
    const int wt = (wave & 1) * 64, wsi = wave >> 1;

    const float* ltp = lt + ((size_t)b * TT + t0) * DD;
    const float* rtp = rt + (size_t)b * TT * DD;
    const float* kmp = km + (size_t)m * DD;
    const int a_t = tid >> 1, a_h = tid & 1;

    f32x4 acc[4][8] = {};

    auto stage = [&](int kk, int buf) {
        const int d0 = kk * BK;
        const float* ap = ltp + (size_t)a_t * DD + d0 + a_h * 16;
        const float* kp = kmp + d0 + a_h * 16;
#pragma unroll
        for (int q = 0; q < 2; ++q) {
            float4 x0 = *(const float4*)(ap + q * 8);
            float4 x1 = *(const float4*)(ap + q * 8 + 4);
            float4 k0 = *(const float4*)(kp + q * 8);
            float4 k1 = *(const float4*)(kp + q * 8 + 4);
            uint4 wv;
            wv.x = pack_bf16(x0.x * k0.x, x0.y * k0.y);
            wv.y = pack_bf16(x0.z * k0.z, x0.w * k0.w);
            wv.z = pack_bf16(x1.x * k1.x, x1.y * k1.y);
            wv.w = pack_bf16(x1.z * k1.z, x1.w * k1.w);
            *(uint4*)&Ash[buf][a_h * 2 + q][a_t][0] = wv;
        }
        const float* bp = rtp + (size_t)tid * DD + d0;
#pragma unroll
        for (int p = 0; p < 4; ++p) {
            float4 y0 = *(const float4*)(bp + p * 8);
            float4 y1 = *(const float4*)(bp + p * 8 + 4);
            uint4 wv;
            wv.x = pack_bf16(y0.x, y0.y);
            wv.y = pack_bf16(y0.z, y0.w);
            wv.z = pack_bf16(y1.x, y1.y);
            wv.w = pack_bf16(y1.z, y1.w);
            *(uint4*)&Bsh2[buf][p][tid][0] = wv;
        }
    };

    stage(0, 0);
    for (int kk = 0; kk < NK; ++kk) {
        const int buf = kk & 1;
        __syncthreads();
        bf16x8 af[4], bfv[8];
#pragma unroll
        for (int i = 0; i < 4; ++i)
            af[i] = *(const bf16x8*)&Ash[buf][l4][wt + i * 16 + l15][0];
#pragma unroll
        for (int j = 0; j < 8; ++j)
            bfv[j] = *(const bf16x8*)&Bsh2[buf][l4][wsi * 128 + j * 16 + l15][0];
        if (kk + 1 < NK) stage(kk + 1, buf ^ 1);
#pragma unroll
        for (int i = 0; i < 4; ++i)
#pragma unroll
            for (int j = 0; j < 8; ++j)
                acc[i][j] = __builtin_amdgcn_mfma_f32_16x16x32_bf16(af[i], bfv[j], acc[i][j], 0, 0, 0);
    }
#pragma unroll
    for (int i = 0; i < 4; ++i) {
        f32x4 v = acc[i][0];
#pragma unroll
        for (int j = 1; j < 8; ++j) {
            v.x = fmaxf(v.x, acc[i][j].x); v.y = fmaxf(v.y, acc[i][j].y);
            v.z = fmaxf(v.z, acc[i][j].z); v.w = fmaxf(v.w, acc[i][j].w);
        }
#pragma unroll
        for (int off = 1; off < 16; off <<= 1) {
            v.x = fmaxf(v.x, __shfl_xor(v.x, off, 64));
            v.y = fmaxf(v.y, __shfl_xor(v.y, off, 64));
            v.z = fmaxf(v.z, __shfl_xor(v.z, off, 64));
            v.w = fmaxf(v.w, __shfl_xor(v.w, off, 64));
        }
        if (l15 == 0) *(f32x4*)&maxbuf[wsi][wt + i * 16 + l4 * 4] = v;
    }
    __syncthreads();
    if (tid < BM) {
        float v = fmaxf(maxbuf[0][tid], maxbuf[1][tid]);
        out[((size_t)b * TT + t0 + tid) * NM + m] = tanhf(v);
    }
}

extern "C" void kernel_launch(void* const* d_in, const int* in_sizes, int n_in,
                              void* d_out, int out_size, void* d_ws, size_t ws_size,
                              hipStream_t stream) {
    const float* lt  = (const float*)d_in[0];   // (32,256,512) fp32
    const float* rt  = (const float*)d_in[1];   // (32,256,512) fp32
    const float* km  = (const float*)d_in[2];   // (20,512) fp32
    float*       out = (float*)d_out;           // (32,256,20) fp32

    const size_t elems = (size_t)NB * TT * DD;                  // 4,194,304 per tensor
    const size_t need  = 2 * elems * sizeof(unsigned short);    // 16 MB

    if (ws_size >= need) {
        unsigned short* ltb = (unsigned short*)d_ws;
        unsigned short* rtb = ltb + elems;
        const int cast_blocks_per_tensor = (int)(elems / (8 * 256));  // 2048
        cast_bf16<<<cast_blocks_per_tensor * 2, 256, 0, stream>>>(lt, rt, ltb, rtb);
        mp_match_main<<<dim3(1280), 256, 0, stream>>>(ltb, rtb, km, out);
    } else {
        mp_match_kernel<<<dim3(TT / BM, NM, NB), 256, 0, stream>>>(lt, rt, km, out);
    }
}

// Round 6
// 132.999 us; speedup vs baseline: 1.1227x; 1.0042x over previous
//
#include <hip/hip_runtime.h>

// MpMaxPoolingMatch: out[b,t,m] = tanh( max_s sum_d lt[b,t,d]*km[m,d]*rt[b,s,d] )
// B=32, T=256, D=512, MP=20.
// R5: occupancy fix. R4's acc[4][8]=128 AGPR + ~100 VGPR = 228/wave -> 2 waves/SIMD.
// Split s across 2 blocks: 128x128 tile, waves 64x64, acc[4][4]=64 AGPR -> 3 waves/SIMD,
// LDS 35 KB, grid 2560 (10/CU). Partial max (pre-tanh) to d_ws; combine kernel applies
// tanh(max(p0,p1)). Keeps R4's XOR-swizzled slabs (0 conflicts) + XCD swizzle (L2-resident).

constexpr int TT = 256;   // T
constexpr int DD = 512;   // D
constexpr int NM = 20;    // MP
constexpr int NB = 32;    // B
constexpr int BM = 128;
constexpr int BN = 256;   // full-s fallback tile
constexpr int BK = 32;
constexpr int NK = DD / BK;   // 16

typedef short bf16x8 __attribute__((ext_vector_type(8)));
typedef float f32x4  __attribute__((ext_vector_type(4)));

__device__ __forceinline__ void async_ld16(const void* g, void* l) {
    __builtin_amdgcn_global_load_lds(
        (const __attribute__((address_space(1))) void*)g,
        (__attribute__((address_space(3))) void*)l, 16, 0, 0);
}

__device__ __forceinline__ unsigned pack_bf16(float lo, float hi) {
    unsigned ulo = __builtin_bit_cast(unsigned, lo);
    unsigned uhi = __builtin_bit_cast(unsigned, hi);
    return (ulo >> 16) | (uhi & 0xFFFF0000u);
}

// scale packed bf16 pair (lo=elem k, hi=elem k+1) by f32 k0,k1; repack (truncate)
__device__ __forceinline__ unsigned mulpack(unsigned a2, float k0, float k1) {
    float f0 = __builtin_bit_cast(float, a2 << 16) * k0;
    float f1 = __builtin_bit_cast(float, a2 & 0xFFFF0000u) * k1;
    return __builtin_amdgcn_perm(__builtin_bit_cast(unsigned, f1),
                                 __builtin_bit_cast(unsigned, f0), 0x07060302u);
}

// ---------------- Phase 1: coalesced fp32 -> bf16 cast, row-major ----------------
__global__ __launch_bounds__(256)
void cast_bf16(const float* __restrict__ lt, const float* __restrict__ rt,
               unsigned short* __restrict__ ltb, unsigned short* __restrict__ rtb)
{
    const int half = (int)gridDim.x >> 1;
    int bid = blockIdx.x;
    const float* src;
    unsigned short* dst;
    if (bid < half) { src = lt; dst = ltb; }
    else            { src = rt; dst = rtb; bid -= half; }
    size_t base = ((size_t)bid * 256 + threadIdx.x) * 8;
    float4 a = *(const float4*)(src + base);
    float4 b = *(const float4*)(src + base + 4);
    uint4 w;
    w.x = pack_bf16(a.x, a.y);
    w.y = pack_bf16(a.z, a.w);
    w.z = pack_bf16(b.x, b.y);
    w.w = pack_bf16(b.z, b.w);
    *(uint4*)(dst + base) = w;
}

// ---------------- Split-s main kernel: 128x128 tile, partial max to ws ----------------
__global__ __launch_bounds__(256, 3)
void mp_match_split(const unsigned short* __restrict__ ltb, const unsigned short* __restrict__ rtb,
                    const float* __restrict__ km, float* __restrict__ part)
{
    // chunk-indexed slabs: chunk = row*4 + pos, pos = c ^ ((row>>1)&3), 16B per chunk
    __shared__ __attribute__((aligned(16))) unsigned short Ash[2][BM * 4 * 8]; // 16 KB
    __shared__ __attribute__((aligned(16))) unsigned short Bsh[2][BM * 4 * 8]; // 16 KB (128 s-rows)
    __shared__ __attribute__((aligned(16))) float kmf[DD];                     // 2 KB
    __shared__ __attribute__((aligned(16))) float maxbuf[2][BM];               // 1 KB

    // XCD swizzle: flat%8 == XCD; b%8 == XCD -> 4 b's (2 MB bf16) per XCD L2.
    const int f  = blockIdx.x;           // 0..2559
    const int c8 = f & 7;
    const int i  = f >> 3;               // 0..319
    const int b  = c8 + 8 * (i / 80);    // 0..31
    const int j  = i % 80;
    const int m  = j >> 2;               // 0..19
    const int t0 = ((j >> 1) & 1) * 128;
    const int s0 = (j & 1) * 128;
    const int sT = j & 1;

    const int tid  = threadIdx.x;
    const int w    = tid >> 6;
    const int lane = tid & 63;
    const int l15  = lane & 15;
    const int l4   = lane >> 4;
    const int wt   = (w & 1) * 64;       // wave's t offset
    const int wsO  = (w >> 1) * 64;      // wave's s offset within 128-tile

    kmf[tid]       = km[(size_t)m * DD + tid];
    kmf[tid + 256] = km[(size_t)m * DD + tid + 256];

    const unsigned short* ltB = ltb + ((size_t)b * TT + t0) * DD;
    const unsigned short* rtB = rtb + ((size_t)b * TT + s0) * DD;

    // A staging: thread handles chunks (row=slot>>2, c=slot&3) for slot=tid, tid+256.
    const int ar0 = tid >> 2,        ac = tid & 3;
    const int ar1 = (tid + 256) >> 2;
    const int ap0 = ac ^ ((ar0 >> 1) & 3);
    const int ap1 = ac ^ ((ar1 >> 1) & 3);
    const unsigned short* aSrc0 = ltB + (size_t)ar0 * DD + ac * 8;
    const unsigned short* aSrc1 = ltB + (size_t)ar1 * DD + ac * 8;

    auto issueB = [&](int kk, int buf) {
        const int kb = kk * BK;
#pragma unroll
        for (int q = 0; q < 2; ++q) {
            int slot = q * 256 + tid;
            int row = slot >> 2;
            int c = (slot & 3) ^ ((slot >> 3) & 3);
            async_ld16(rtB + (size_t)row * DD + kb + c * 8,
                       (char*)&Bsh[buf][0] + (size_t)slot * 16);
        }
    };
    auto aload = [&](int kk, uint4* ar) {
        ar[0] = *(const uint4*)(aSrc0 + kk * BK);
        ar[1] = *(const uint4*)(aSrc1 + kk * BK);
    };
    auto scaleWrite = [&](int kk, int buf, const uint4* ar) {
        float4 k0 = *(const float4*)&kmf[kk * BK + ac * 8];
        float4 k1 = *(const float4*)&kmf[kk * BK + ac * 8 + 4];
        uint4 o;
        o.x = mulpack(ar[0].x, k0.x, k0.y);
        o.y = mulpack(ar[0].y, k0.z, k0.w);
        o.z = mulpack(ar[0].z, k1.x, k1.y);
        o.w = mulpack(ar[0].w, k1.z, k1.w);
        *(uint4*)&Ash[buf][(size_t)(ar0 * 4 + ap0) * 8] = o;
        o.x = mulpack(ar[1].x, k0.x, k0.y);
        o.y = mulpack(ar[1].y, k0.z, k0.w);
        o.z = mulpack(ar[1].z, k1.x, k1.y);
        o.w = mulpack(ar[1].w, k1.z, k1.w);
        *(uint4*)&Ash[buf][(size_t)(ar1 * 4 + ap1) * 8] = o;
    };

    f32x4 acc[4][4] = {};
    uint4 ar[2];

    aload(0, ar);
    issueB(0, 0);
    __syncthreads();       // kmf visible; prologue loads+DMA drained
    scaleWrite(0, 0, ar);

    const int fpos = l4 ^ ((l15 >> 1) & 3);

    for (int kk = 0; kk < NK; ++kk) {
        const int buf = kk & 1;
        __syncthreads();
        if (kk + 1 < NK) {
            aload(kk + 1, ar);
            issueB(kk + 1, buf ^ 1);
        }
        bf16x8 af[4], bv[4];
#pragma unroll
        for (int ii = 0; ii < 4; ++ii)
            af[ii] = *(const bf16x8*)&Ash[buf][(size_t)((wt + ii * 16 + l15) * 4 + fpos) * 8];
#pragma unroll
        for (int jj = 0; jj < 4; ++jj)
            bv[jj] = *(const bf16x8*)&Bsh[buf][(size_t)((wsO + jj * 16 + l15) * 4 + fpos) * 8];
#pragma unroll
        for (int ii = 0; ii < 4; ++ii)
#pragma unroll
            for (int jj = 0; jj < 4; ++jj)
                acc[ii][jj] = __builtin_amdgcn_mfma_f32_16x16x32_bf16(af[ii], bv[jj], acc[ii][jj], 0, 0, 0);
        if (kk + 1 < NK)
            scaleWrite(kk + 1, buf ^ 1, ar);
    }

    // ---- Epilogue: max over this block's 128 s (NO tanh yet). C layout: col=lane&15, row=(lane>>4)*4+reg.
#pragma unroll
    for (int ii = 0; ii < 4; ++ii) {
        f32x4 v = acc[ii][0];
#pragma unroll
        for (int jj = 1; jj < 4; ++jj) {
            v.x = fmaxf(v.x, acc[ii][jj].x);
            v.y = fmaxf(v.y, acc[ii][jj].y);
            v.z = fmaxf(v.z, acc[ii][jj].z);
            v.w = fmaxf(v.w, acc[ii][jj].w);
        }
#pragma unroll
        for (int off = 1; off < 16; off <<= 1) {
            v.x = fmaxf(v.x, __shfl_xor(v.x, off, 64));
            v.y = fmaxf(v.y, __shfl_xor(v.y, off, 64));
            v.z = fmaxf(v.z, __shfl_xor(v.z, off, 64));
            v.w = fmaxf(v.w, __shfl_xor(v.w, off, 64));
        }
        if (l15 == 0)
            *(f32x4*)&maxbuf[w >> 1][wt + ii * 16 + l4 * 4] = v;
    }
    __syncthreads();
    if (tid < BM) {
        float v = fmaxf(maxbuf[0][tid], maxbuf[1][tid]);
        part[(((size_t)sT * NB + b) * TT + t0 + tid) * NM + m] = v;
    }
}

// ---------------- Combine: out = tanh(max(p0, p1)) ----------------
__global__ __launch_bounds__(256)
void mp_combine(const float* __restrict__ part, float* __restrict__ out, int n)
{
    int idx = blockIdx.x * 256 + threadIdx.x;
    if (idx < n)
        out[idx] = tanhf(fmaxf(part[idx], part[(size_t)n + idx]));
}

// ---------------- R4 full-s main (fallback tier 2, ws >= 16 MB) ----------------
__global__ __launch_bounds__(256, 2)
void mp_match_main(const unsigned short* __restrict__ ltb, const unsigned short* __restrict__ rtb,
                   const float* __restrict__ km, float* __restrict__ out)
{
    __shared__ __attribute__((aligned(16))) unsigned short Bsh[2][BN * 4 * 8]; // 32 KB
    __shared__ __attribute__((aligned(16))) unsigned short Ash[2][BM * 4 * 8]; // 16 KB
    __shared__ __attribute__((aligned(16))) float kmf[DD];
    __shared__ __attribute__((aligned(16))) float maxbuf[2][BM];

    const int f = blockIdx.x;
    const int c8 = f & 7;
    const int i = f >> 3;
    const int b = c8 + 8 * (i / 40);
    const int j = i % 40;
    const int m = j >> 1;
    const int t0 = (j & 1) * BM;

    const int tid  = threadIdx.x;
    const int w    = tid >> 6;
    const int lane = tid & 63;
    const int l15  = lane & 15;
    const int l4   = lane >> 4;
    const int wt   = (w & 1) * 64;
    const int wsi  = w >> 1;

    kmf[tid]       = km[(size_t)m * DD + tid];
    kmf[tid + 256] = km[(size_t)m * DD + tid + 256];

    const unsigned short* ltB = ltb + ((size_t)b * TT + t0) * DD;
    const unsigned short* rtB = rtb + (size_t)b * TT * DD;

    const int ar0 = tid >> 2,        ac = tid & 3;
    const int ar1 = (tid + 256) >> 2;
    const int ap0 = ac ^ ((ar0 >> 1) & 3);
    const int ap1 = ac ^ ((ar1 >> 1) & 3);
    const unsigned short* aSrc0 = ltB + (size_t)ar0 * DD + ac * 8;
    const unsigned short* aSrc1 = ltB + (size_t)ar1 * DD + ac * 8;

    auto issueB = [&](int kk, int buf) {
        const int kb = kk * BK;
#pragma unroll
        for (int q = 0; q < 4; ++q) {
            int slot = q * 256 + tid;
            int row = slot >> 2;
            int c = (slot & 3) ^ ((slot >> 3) & 3);
            async_ld16(rtB + (size_t)row * DD + kb + c * 8,
                       (char*)&Bsh[buf][0] + (size_t)slot * 16);
        }
    };
    auto aload = [&](int kk, uint4* ar) {
        ar[0] = *(const uint4*)(aSrc0 + kk * BK);
        ar[1] = *(const uint4*)(aSrc1 + kk * BK);
    };
    auto scaleWrite = [&](int kk, int buf, const uint4* ar) {
        float4 k0 = *(const float4*)&kmf[kk * BK + ac * 8];
        float4 k1 = *(const float4*)&kmf[kk * BK + ac * 8 + 4];
        uint4 o;
        o.x = mulpack(ar[0].x, k0.x, k0.y);
        o.y = mulpack(ar[0].y, k0.z, k0.w);
        o.z = mulpack(ar[0].z, k1.x, k1.y);
        o.w = mulpack(ar[0].w, k1.z, k1.w);
        *(uint4*)&Ash[buf][(size_t)(ar0 * 4 + ap0) * 8] = o;
        o.x = mulpack(ar[1].x, k0.x, k0.y);
        o.y = mulpack(ar[1].y, k0.z, k0.w);
        o.z = mulpack(ar[1].z, k1.x, k1.y);
        o.w = mulpack(ar[1].w, k1.z, k1.w);
        *(uint4*)&Ash[buf][(size_t)(ar1 * 4 + ap1) * 8] = o;
    };

    f32x4 acc[4][8] = {};
    uint4 ar[2];

    aload(0, ar);
    issueB(0, 0);
    __syncthreads();
    scaleWrite(0, 0, ar);

    const int fpos = l4 ^ ((l15 >> 1) & 3);

    for (int kk = 0; kk < NK; ++kk) {
        const int buf = kk & 1;
        __syncthreads();
        if (kk + 1 < NK) {
            aload(kk + 1, ar);
            issueB(kk + 1, buf ^ 1);
        }
        bf16x8 af[4], bv[8];
#pragma unroll
        for (int ii = 0; ii < 4; ++ii)
            af[ii] = *(const bf16x8*)&Ash[buf][(size_t)((wt + ii * 16 + l15) * 4 + fpos) * 8];
#pragma unroll
        for (int jj = 0; jj < 8; ++jj)
            bv[jj] = *(const bf16x8*)&Bsh[buf][(size_t)((wsi * 128 + jj * 16 + l15) * 4 + fpos) * 8];
#pragma unroll
        for (int ii = 0; ii < 4; ++ii)
#pragma unroll
            for (int jj = 0; jj < 8; ++jj)
                acc[ii][jj] = __builtin_amdgcn_mfma_f32_16x16x32_bf16(af[ii], bv[jj], acc[ii][jj], 0, 0, 0);
        if (kk + 1 < NK)
            scaleWrite(kk + 1, buf ^ 1, ar);
    }

#pragma unroll
    for (int ii = 0; ii < 4; ++ii) {
        f32x4 v = acc[ii][0];
#pragma unroll
        for (int jj = 1; jj < 8; ++jj) {
            v.x = fmaxf(v.x, acc[ii][jj].x);
            v.y = fmaxf(v.y, acc[ii][jj].y);
            v.z = fmaxf(v.z, acc[ii][jj].z);
            v.w = fmaxf(v.w, acc[ii][jj].w);
        }
#pragma unroll
        for (int off = 1; off < 16; off <<= 1) {
            v.x = fmaxf(v.x, __shfl_xor(v.x, off, 64));
            v.y = fmaxf(v.y, __shfl_xor(v.y, off, 64));
            v.z = fmaxf(v.z, __shfl_xor(v.z, off, 64));
            v.w = fmaxf(v.w, __shfl_xor(v.w, off, 64));
        }
        if (l15 == 0)
            *(f32x4*)&maxbuf[wsi][wt + ii * 16 + l4 * 4] = v;
    }
    __syncthreads();
    if (tid < BM) {
        float v = fmaxf(maxbuf[0][tid], maxbuf[1][tid]);
        out[((size_t)b * TT + t0 + tid) * NM + m] = tanhf(v);
    }
}

// ---------------- R1 fallback (no workspace) ----------------
__global__ __launch_bounds__(256, 2)
void mp_match_kernel(const float* __restrict__ lt, const float* __restrict__ rt,
                     const float* __restrict__ km, float* __restrict__ out)
{
    __shared__ __attribute__((aligned(16))) unsigned short Ash[2][4][BM][8];
    __shared__ __attribute__((aligned(16))) unsigned short Bsh2[2][4][BN][8];
    __shared__ __attribute__((aligned(16))) float maxbuf[2][BM];

    const int ttile = blockIdx.x, m = blockIdx.y, b = blockIdx.z;
    const int t0 = ttile * BM;
    const int tid = threadIdx.x, wave = tid >> 6, lane = tid & 63;
    const int l15 = lane & 15, l4 = lane >> 4;
    const int wt = (wave & 1) * 64, wsi = wave >> 1;

    const float* ltp = lt + ((size_t)b * TT + t0) * DD;
    const float* rtp = rt + (size_t)b * TT * DD;
    const float* kmp = km + (size_t)m * DD;
    const int a_t = tid >> 1, a_h = tid & 1;

    f32x4 acc[4][8] = {};

    auto stage = [&](int kk, int buf) {
        const int d0 = kk * BK;
        const float* ap = ltp + (size_t)a_t * DD + d0 + a_h * 16;
        const float* kp = kmp + d0 + a_h * 16;
#pragma unroll
        for (int q = 0; q < 2; ++q) {
            float4 x0 = *(const float4*)(ap + q * 8);
            float4 x1 = *(const float4*)(ap + q * 8 + 4);
            float4 k0 = *(const float4*)(kp + q * 8);
            float4 k1 = *(const float4*)(kp + q * 8 + 4);
            uint4 wv;
            wv.x = pack_bf16(x0.x * k0.x, x0.y * k0.y);
            wv.y = pack_bf16(x0.z * k0.z, x0.w * k0.w);
            wv.z = pack_bf16(x1.x * k1.x, x1.y * k1.y);
            wv.w = pack_bf16(x1.z * k1.z, x1.w * k1.w);
            *(uint4*)&Ash[buf][a_h * 2 + q][a_t][0] = wv;
        }
        const float* bp = rtp + (size_t)tid * DD + d0;
#pragma unroll
        for (int p = 0; p < 4; ++p) {
            float4 y0 = *(const float4*)(bp + p * 8);
            float4 y1 = *(const float4*)(bp + p * 8 + 4);
            uint4 wv;
            wv.x = pack_bf16(y0.x, y0.y);
            wv.y = pack_bf16(y0.z, y0.w);
            wv.z = pack_bf16(y1.x, y1.y);
            wv.w = pack_bf16(y1.z, y1.w);
            *(uint4*)&Bsh2[buf][p][tid][0] = wv;
        }
    };

    stage(0, 0);
    for (int kk = 0; kk < NK; ++kk) {
        const int buf = kk & 1;
        __syncthreads();
        bf16x8 af[4], bfv[8];
#pragma unroll
        for (int i = 0; i < 4; ++i)
            af[i] = *(const bf16x8*)&Ash[buf][l4][wt + i * 16 + l15][0];
#pragma unroll
        for (int j = 0; j < 8; ++j)
            bfv[j] = *(const bf16x8*)&Bsh2[buf][l4][wsi * 128 + j * 16 + l15][0];
        if (kk + 1 < NK) stage(kk + 1, buf ^ 1);
#pragma unroll
        for (int i = 0; i < 4; ++i)
#pragma unroll
            for (int j = 0; j < 8; ++j)
                acc[i][j] = __builtin_amdgcn_mfma_f32_16x16x32_bf16(af[i], bfv[j], acc[i][j], 0, 0, 0);
    }
#pragma unroll
    for (int i = 0; i < 4; ++i) {
        f32x4 v = acc[i][0];
#pragma unroll
        for (int j = 1; j < 8; ++j) {
            v.x = fmaxf(v.x, acc[i][j].x); v.y = fmaxf(v.y, acc[i][j].y);
            v.z = fmaxf(v.z, acc[i][j].z); v.w = fmaxf(v.w, acc[i][j].w);
        }
#pragma unroll
        for (int off = 1; off < 16; off <<= 1) {
            v.x = fmaxf(v.x, __shfl_xor(v.x, off, 64));
            v.y = fmaxf(v.y, __shfl_xor(v.y, off, 64));
            v.z = fmaxf(v.z, __shfl_xor(v.z, off, 64));
            v.w = fmaxf(v.w, __shfl_xor(v.w, off, 64));
        }
        if (l15 == 0) *(f32x4*)&maxbuf[wsi][wt + i * 16 + l4 * 4] = v;
    }
    __syncthreads();
    if (tid < BM) {
        float v = fmaxf(maxbuf[0][tid], maxbuf[1][tid]);
        out[((size_t)b * TT + t0 + tid) * NM + m] = tanhf(v);
    }
}

extern "C" void kernel_launch(void* const* d_in, const int* in_sizes, int n_in,
                              void* d_out, int out_size, void* d_ws, size_t ws_size,
                              hipStream_t stream) {
    const float* lt  = (const float*)d_in[0];   // (32,256,512) fp32
    const float* rt  = (const float*)d_in[1];   // (32,256,512) fp32
    const float* km  = (const float*)d_in[2];   // (20,512) fp32
    float*       out = (float*)d_out;           // (32,256,20) fp32

    const size_t elems = (size_t)NB * TT * DD;                  // 4,194,304 per tensor
    const size_t castB = 2 * elems * sizeof(unsigned short);    // 16 MB
    const int    nOut  = NB * TT * NM;                          // 163,840
    const size_t partB = 2 * (size_t)nOut * sizeof(float);      // 1.31 MB

    if (ws_size >= castB + partB) {
        unsigned short* ltb = (unsigned short*)d_ws;
        unsigned short* rtb = ltb + elems;
        float* part = (float*)((char*)d_ws + castB);
        cast_bf16<<<4096, 256, 0, stream>>>(lt, rt, ltb, rtb);
        mp_match_split<<<2560, 256, 0, stream>>>(ltb, rtb, km, part);
        mp_combine<<<(nOut + 255) / 256, 256, 0, stream>>>(part, out, nOut);
    } else if (ws_size >= castB) {
        unsigned short* ltb = (unsigned short*)d_ws;
        unsigned short* rtb = ltb + elems;
        cast_bf16<<<4096, 256, 0, stream>>>(lt, rt, ltb, rtb);
        mp_match_main<<<1280, 256, 0, stream>>>(ltb, rtb, km, out);
    } else {
        mp_match_kernel<<<dim3(TT / BM, NM, NB), 256, 0, stream>>>(lt, rt, km, out);
    }
}